// Round 16
// baseline (3001.951 us; speedup 1.0000x reference)
//
#include <hip/hip_runtime.h>
#include <hip/hip_bf16.h>

#define BB 64
#define SS 512
#define HH 1024
#define G4 4096

using bf8_t = __attribute__((ext_vector_type(8))) short;   // 8 bf16 (4 VGPRs)
using f32x4 = __attribute__((ext_vector_type(4))) float;   // 4 fp32 acc
typedef unsigned long long ull;

__device__ inline ushort f2bf(float f) {
  __hip_bfloat16 h = __float2bfloat16(f);
  return *reinterpret_cast<ushort*>(&h);
}
__device__ inline float bf2f(ushort u) {
  unsigned v = ((unsigned)u) << 16;
  return __uint_as_float(v);
}

// fp32 [R][C] -> bf16 [C][R]
__global__ __launch_bounds__(256) void k_transpose_cast(
    const float* __restrict__ in, ushort* __restrict__ out, int R, int C) {
  __shared__ float tile[32][33];
  int c0 = blockIdx.x * 32, r0 = blockIdx.y * 32;
  int tx = threadIdx.x & 31, ty = threadIdx.x >> 5;  // 32 x 8
  for (int i = ty; i < 32; i += 8) {
    int r = r0 + i, c = c0 + tx;
    tile[i][tx] = (r < R && c < C) ? in[(size_t)r * C + c] : 0.f;
  }
  __syncthreads();
  for (int i = ty; i < 32; i += 8) {
    int c = c0 + i, r = r0 + tx;
    if (c < C && r < R) out[(size_t)c * R + r] = f2bf(tile[tx][i]);
  }
}

// Ae[row = t*64+b][k] = embed_tok[x[b][t]][k] + embed_pos[t][k], bf16
__global__ __launch_bounds__(256) void k_embed(
    const int* __restrict__ x, const float* __restrict__ etok,
    const float* __restrict__ epos, ushort* __restrict__ Ae) {
  int row = blockIdx.x;
  int t = row >> 6, b = row & 63;
  int tok = x[b * SS + t];
  const float4* tp = (const float4*)(etok + (size_t)tok * HH);
  const float4* pp = (const float4*)(epos + (size_t)t * HH);
  int i = threadIdx.x;  // 256 threads * float4 = 1024
  float4 a = tp[i], p = pp[i];
  ushort4 r = make_ushort4(f2bf(a.x + p.x), f2bf(a.y + p.y),
                           f2bf(a.z + p.z), f2bf(a.w + p.w));
  ((ushort4*)(Ae + (size_t)row * HH))[i] = r;
}

// C[m][n] (bf16) = A[m][k] @ Bt[n][k]^T + bias[n].  M,N mult of 128, K=1024.
// m97-structure: global_load_lds width=16 staging, linear LDS, 128^2 tile.
__global__ __launch_bounds__(256) void k_gemm_xi(
    const ushort* __restrict__ Ag, const ushort* __restrict__ Bt,
    const float* __restrict__ bias, ushort* __restrict__ Cout, int N) {
  __shared__ alignas(16) ushort As[128 * 32];   // linear (gload_lds needs it)
  __shared__ alignas(16) ushort Bs[128 * 32];
  const int m0 = blockIdx.y * 128, n0 = blockIdx.x * 128;
  const int tid = threadIdx.x;
  const int w = tid >> 6, lane = tid & 63;
  const int wm = w >> 1, wn = w & 1;            // 2x2 waves, 64x64 each
  const int lr = lane & 15, kq = lane >> 4;
  const int srow = w * 32 + (lane >> 2);
  const int skq8 = (lane & 3) * 8;              // shorts offset within row
  f32x4 acc[4][4] = {};
  for (int k0 = 0; k0 < HH; k0 += 32) {
    __syncthreads();    // previous iter's ds_reads done before overwrite
    const ushort* ga0 = Ag + (size_t)(m0 + srow) * HH + k0 + skq8;
    const ushort* gb0 = Bt + (size_t)(n0 + srow) * HH + k0 + skq8;
    __builtin_amdgcn_global_load_lds(
        (const __attribute__((address_space(1))) unsigned*)ga0,
        (__attribute__((address_space(3))) unsigned*)&As[(w * 32) * 32], 16, 0, 0);
    __builtin_amdgcn_global_load_lds(
        (const __attribute__((address_space(1))) unsigned*)(ga0 + 16 * HH),
        (__attribute__((address_space(3))) unsigned*)&As[(w * 32 + 16) * 32], 16, 0, 0);
    __builtin_amdgcn_global_load_lds(
        (const __attribute__((address_space(1))) unsigned*)gb0,
        (__attribute__((address_space(3))) unsigned*)&Bs[(w * 32) * 32], 16, 0, 0);
    __builtin_amdgcn_global_load_lds(
        (const __attribute__((address_space(1))) unsigned*)(gb0 + 16 * HH),
        (__attribute__((address_space(3))) unsigned*)&Bs[(w * 32 + 16) * 32], 16, 0, 0);
    __syncthreads();    // drains vmcnt (gload_lds) per syncthreads semantics
    bf8_t fa[4], fb[4];
#pragma unroll
    for (int i = 0; i < 4; ++i) {
      fa[i] = *(const bf8_t*)&As[(wm * 64 + i * 16 + lr) * 32 + kq * 8];
      fb[i] = *(const bf8_t*)&Bs[(wn * 64 + i * 16 + lr) * 32 + kq * 8];
    }
#pragma unroll
    for (int mi = 0; mi < 4; ++mi)
#pragma unroll
      for (int ni = 0; ni < 4; ++ni)
        acc[mi][ni] = __builtin_amdgcn_mfma_f32_16x16x32_bf16(fa[mi], fb[ni], acc[mi][ni], 0, 0, 0);
  }
#pragma unroll
  for (int mi = 0; mi < 4; ++mi) {
    int grow = m0 + wm * 64 + mi * 16 + kq * 4;
#pragma unroll
    for (int ni = 0; ni < 4; ++ni) {
      int gcol = n0 + wn * 64 + ni * 16 + lr;
      float bv = bias[gcol];
#pragma unroll
      for (int r = 0; r < 4; ++r)
        Cout[(size_t)(grow + r) * N + gcol] = f2bf(acc[mi][ni][r] + bv);
    }
  }
}

// Persistent recurrence (r10 transport — empirically fastest AND the only
// L2-stale-proof consume path: ALL fragA reads are agent-scope atomic loads,
// which bypass L2; plain loads of a MALL-published buffer are unsound (r15)).
// Mixed-gate B layout: wave w lane(kq,lr): gate=lr>>2, col=n0+4w+(lr&3)
// -> parallel shfl epilogue, 0 bank conflicts.
// Poll: round 1 reads all 16 x 8B units; retries re-read ONLY incomplete
// batches via a wave-uniform miss mask (__all per batch -> uniform branch,
// no per-lane serialization). No sleep backoff (r14: it regresses).
__global__ __launch_bounds__(256, 1) void k_recur(
    const ushort* __restrict__ Wh_t,   // [4096][1024] bf16
    const ushort* __restrict__ xi,     // [S*64][4096] bf16 (bh folded in)
    ushort* __restrict__ hs,           // [(S+1)*64][1024] bf16 row layout
    uint4* __restrict__ fragA) {       // [512][4][2048] 16B units; sentinel-filled
  __shared__ alignas(16) ushort htile[2048 * 8];   // 32 KiB
  __shared__ ushort hxch[4][16][4];                // 512 B wave-local transpose
  const ull SENT = 0x7F7F7F7F7F7F7F7FULL;
  const int grp = blockIdx.x >> 6;      // batch group 0..3
  const int mem = blockIdx.x & 63;      // member (column owner)
  const int n0 = mem * 16;
  const int brow0 = grp * 16;
  const int tid = threadIdx.x;
  const int w = tid >> 6, lane = tid & 63;
  const int lr = lane & 15, kq = lane >> 4;
  const int gate = lr >> 2;
  const int c0 = n0 + 4 * w;            // wave's 4-col base
  const int gc = gate * 1024 + c0 + (lr & 3);

  // fb fragments via inline-asm loads (32-batch proven safe)
  bf8_t fbr[32];
  {
    const ushort* wrow = Wh_t + (size_t)gc * HH + kq * 8;
#pragma unroll
    for (int k = 0; k < 32; ++k)
      asm volatile("global_load_dwordx4 %0, %1, off offset:%c2"
                   : "=v"(fbr[k]) : "v"(wrow), "i"(k * 64));
    asm volatile("s_waitcnt vmcnt(0)" ::: "memory");
  }

  // publish precompute (lanes 0..15): unit u = pk0*64+pq*16+row, byte pboff
  const int pk0 = c0 >> 5, pq = (c0 >> 3) & 3;
  const int pboff = (c0 & 7) * 2;       // 0 or 8

  float cr[4] = {0.f, 0.f, 0.f, 0.f};   // c-state

  // xi(0) preload: xi[row=brow0+kq*4+r][gc]
  ushort xv[4];
  {
    const ushort* xr = xi + ((size_t)brow0 + kq * 4) * G4 + gc;
#pragma unroll
    for (int r = 0; r < 4; ++r) xv[r] = xr[(size_t)r * G4];
  }

  for (int t = 0; t < SS; ++t) {
    // ---- obtain h(t): batched sentinel poll, batch-skip retries ----
    ull uvv[16];
    if (t == 0) {
#pragma unroll
      for (int j = 0; j < 16; ++j) uvv[j] = 0;
    } else {
      const ull* q = (const ull*)(fragA + ((size_t)(t - 1) * 4 + grp) * 2048);
#pragma unroll
      for (int i = 0; i < 8; ++i) {     // round 1: all 16 loads in flight
        uvv[2 * i]     = __hip_atomic_load(q + 2 * tid + 512 * i,
                            __ATOMIC_RELAXED, __HIP_MEMORY_SCOPE_AGENT);
        uvv[2 * i + 1] = __hip_atomic_load(q + 2 * tid + 512 * i + 1,
                            __ATOMIC_RELAXED, __HIP_MEMORY_SCOPE_AGENT);
      }
      unsigned miss = 0;
#pragma unroll
      for (int i = 0; i < 8; ++i) {     // wave-uniform miss mask per batch
        bool ok = (uvv[2 * i] != SENT) & (uvv[2 * i + 1] != SENT);
        if (!__all(ok)) miss |= (1u << i);
      }
      while (miss) {                    // retries touch ONLY missing batches
#pragma unroll
        for (int i = 0; i < 8; ++i) {
          if (miss & (1u << i)) {       // wave-uniform branch
            uvv[2 * i]     = __hip_atomic_load(q + 2 * tid + 512 * i,
                                __ATOMIC_RELAXED, __HIP_MEMORY_SCOPE_AGENT);
            uvv[2 * i + 1] = __hip_atomic_load(q + 2 * tid + 512 * i + 1,
                                __ATOMIC_RELAXED, __HIP_MEMORY_SCOPE_AGENT);
          }
        }
        unsigned m2 = 0;
#pragma unroll
        for (int i = 0; i < 8; ++i) {
          if (miss & (1u << i)) {
            bool ok = (uvv[2 * i] != SENT) & (uvv[2 * i + 1] != SENT);
            if (!__all(ok)) m2 |= (1u << i);
          }
        }
        miss = m2;
      }
    }
    __syncthreads();                    // A: all waves done reading old htile

    // ---- stage 32KB tile (fragment-linear, conflict-free) ----
#pragma unroll
    for (int i = 0; i < 8; ++i) {
      uint4 sw;
      sw.x = (unsigned)uvv[2 * i];     sw.y = (unsigned)(uvv[2 * i] >> 32);
      sw.z = (unsigned)uvv[2 * i + 1]; sw.w = (unsigned)(uvv[2 * i + 1] >> 32);
      *(uint4*)&htile[(size_t)(tid + 256 * i) * 8] = sw;
    }
    __syncthreads();                    // B: stage complete

    // xi(t+1) prefetch — consumed next step, hidden under MFMA
    ushort xn[4];
    {
      int tn = (t + 1 < SS) ? t + 1 : t;
      const ushort* xr = xi + ((size_t)tn * 64 + brow0 + kq * 4) * G4 + gc;
#pragma unroll
      for (int r = 0; r < 4; ++r) xn[r] = xr[(size_t)r * G4];
    }

    // ---- MFMA: 32 k-chunks, fa LDS conflict-free, fb regs ----
    f32x4 acc0 = {}, acc1 = {};
#pragma unroll
    for (int k = 0; k < 32; k += 2) {
      bf8_t fa0 = *(const bf8_t*)&htile[(k * 64 + lane) * 8];
      bf8_t fa1 = *(const bf8_t*)&htile[((k + 1) * 64 + lane) * 8];
      acc0 = __builtin_amdgcn_mfma_f32_16x16x32_bf16(fa0, fbr[k], acc0, 0, 0, 0);
      acc1 = __builtin_amdgcn_mfma_f32_16x16x32_bf16(fa1, fbr[k + 1], acc1, 0, 0, 0);
    }

    // ---- parallel epilogue (all lanes) ----
    float z[4], zb[4], zc[4], zd[4];
#pragma unroll
    for (int r = 0; r < 4; ++r) z[r] = acc0[r] + acc1[r] + bf2f(xv[r]);
#pragma unroll
    for (int r = 0; r < 4; ++r) {
      zb[r] = __shfl_xor(z[r], 4);
      zc[r] = __shfl_xor(z[r], 8);
      zd[r] = __shfl_xor(zb[r], 8);
    }
    ushort hvals[4];
#pragma unroll
    for (int r = 0; r < 4; ++r) {
      float zi = gate == 0 ? z[r] : gate == 1 ? zb[r] : gate == 2 ? zc[r] : zd[r];
      float zf = gate == 0 ? zb[r] : gate == 1 ? z[r] : gate == 2 ? zd[r] : zc[r];
      float zg = gate == 0 ? zc[r] : gate == 1 ? zd[r] : gate == 2 ? z[r] : zb[r];
      float zo = gate == 0 ? zd[r] : gate == 1 ? zc[r] : gate == 2 ? zb[r] : z[r];
      float si = 1.f / (1.f + __expf(-zi));
      float sf = 1.f / (1.f + __expf(-zf));
      float so = 1.f / (1.f + __expf(-zo));
      float tg = 1.f - 2.f / (1.f + __expf(2.f * zg));   // tanh
      float c  = sf * cr[r] + si * tg;
      cr[r] = c;
      float tc = 1.f - 2.f / (1.f + __expf(2.f * c));    // tanh
      hvals[r] = f2bf(so * tc);
    }
    // wave-local transpose: gate-0 lanes write (4 rows x 1 col each)
    if (lr < 4) {
#pragma unroll
      for (int r = 0; r < 4; ++r) hxch[w][kq * 4 + r][lr] = hvals[r];
    }
    // lanes 0..15: read (row=lane, 4 cols) and publish (same wave -> lgkmcnt)
    if (lane < 16) {
      uint2 ho8 = *(const uint2*)&hxch[w][lane][0];
      ull val = ((ull)ho8.y << 32) | ho8.x;
      char* fbase = (char*)(fragA + ((size_t)t * 4 + grp) * 2048);
      ull* fdst = (ull*)(fbase + (size_t)(pk0 * 64 + pq * 16 + lane) * 16 + pboff);
      __hip_atomic_exchange(fdst, val, __ATOMIC_RELAXED,
                            __HIP_MEMORY_SCOPE_AGENT);   // fire-and-forget
      // row-layout copy for k_logits (read only after kernel end)
      *(uint2*)(hs + ((size_t)(t + 1) * 64 + brow0 + lane) * HH + c0) = ho8;
    }
    xv[0] = xn[0]; xv[1] = xn[1]; xv[2] = xn[2]; xv[3] = xn[3];
  }
}

// logits[b][t][a] = hs[t+1][b][:] . Wd_t[a][:] + bd[a]
__global__ __launch_bounds__(256) void k_logits(
    const ushort* __restrict__ hs1, const ushort* __restrict__ Wdt,
    const float* __restrict__ bd, float* __restrict__ out) {
  int gid = blockIdx.x * 256 + threadIdx.x;
  int a = gid & 15, row = gid >> 4;   // row = t*64+b
  int t = row >> 6, b = row & 63;
  const uint4* hp = (const uint4*)(hs1 + (size_t)row * HH);
  const uint4* wp = (const uint4*)(Wdt + (size_t)a * HH);
  float sum = 0.f;
#pragma unroll 4
  for (int i = 0; i < HH / 8; ++i) {
    uint4 hv = hp[i], wv = wp[i];
    const uint* hu = (const uint*)&hv;
    const uint* wu = (const uint*)&wv;
#pragma unroll
    for (int j = 0; j < 4; ++j) {
      sum += bf2f((ushort)(hu[j] & 0xffff)) * bf2f((ushort)(wu[j] & 0xffff));
      sum += bf2f((ushort)(hu[j] >> 16)) * bf2f((ushort)(wu[j] >> 16));
    }
  }
  out[32768 + ((size_t)b * SS + t) * 16 + a] = sum + bd[a];
}

extern "C" void kernel_launch(void* const* d_in, const int* in_sizes, int n_in,
                              void* d_out, int out_size, void* d_ws, size_t ws_size,
                              hipStream_t stream) {
  const int*   x    = (const int*)d_in[0];
  const float* etok = (const float*)d_in[4];
  const float* epos = (const float*)d_in[5];
  const float* Wi   = (const float*)d_in[6];
  const float* Wh   = (const float*)d_in[7];
  const float* bh   = (const float*)d_in[8];
  const float* Wd   = (const float*)d_in[9];
  const float* bd   = (const float*)d_in[10];

  char* ws = (char*)d_ws;
  size_t off = 0;
  ushort* Wi_t = (ushort*)(ws + off); off += (size_t)G4 * HH * 2;            // 8 MB
  ushort* Wh_t = (ushort*)(ws + off); off += (size_t)G4 * HH * 2;            // 8 MB
  ushort* Wd_t = (ushort*)(ws + off); off += 65536;                          // 64 KB
  // Ae (64 MB, dead after k_gemm_xi) aliases fragA (64 MB). Sentinel memset
  // sits between them in stream order; all k_recur consumes are atomic
  // (L2-bypass) so stale clean lines are unreachable.
  char* AeFrag = ws + off;            off += (size_t)512 * 4 * 2048 * 16;    // 64 MB
  ushort* Ae   = (ushort*)AeFrag;
  uint4*  fragA = (uint4*)AeFrag;
  ushort* xi   = (ushort*)(ws + off); off += (size_t)BB * SS * G4 * 2;       // 256 MB
  ushort* hs   = (ushort*)(ws + off); off += (size_t)(SS + 1) * BB * HH * 2; // 64.1 MB

  hipMemsetAsync(d_out, 0, (size_t)out_size * 4, stream);          // dummies = 0

  dim3 b256(256);
  k_transpose_cast<<<dim3(G4 / 32, HH / 32), b256, 0, stream>>>(Wi, Wi_t, HH, G4);
  k_transpose_cast<<<dim3(G4 / 32, HH / 32), b256, 0, stream>>>(Wh, Wh_t, HH, G4);
  k_transpose_cast<<<dim3(1, HH / 32), b256, 0, stream>>>(Wd, Wd_t, HH, 16);
  k_embed<<<BB * SS, b256, 0, stream>>>(x, etok, epos, Ae);
  k_gemm_xi<<<dim3(G4 / 128, BB * SS / 128), b256, 0, stream>>>(Ae, Wi_t, bh, xi, G4);
  // re-sentinel fragA EVERY call (harness replays without re-poisoning)
  hipMemsetAsync(fragA, 0x7F, (size_t)512 * 4 * 2048 * 16, stream);
  k_recur<<<256, b256, 0, stream>>>(Wh_t, xi, hs, fragA);
  k_logits<<<BB * SS * 16 / 256, b256, 0, stream>>>(hs + (size_t)BB * HH, Wd_t, bd,
                                                    (float*)d_out);
}

// Round 17
// 2767.516 us; speedup vs baseline: 1.0847x; 1.0847x over previous
//
#include <hip/hip_runtime.h>
#include <hip/hip_bf16.h>

#define BB 64
#define SS 512
#define HH 1024
#define G4 4096

using bf8_t = __attribute__((ext_vector_type(8))) short;   // 8 bf16 (4 VGPRs)
using f32x4 = __attribute__((ext_vector_type(4))) float;   // 4 fp32 acc
typedef unsigned long long ull;

__device__ inline ushort f2bf(float f) {
  __hip_bfloat16 h = __float2bfloat16(f);
  return *reinterpret_cast<ushort*>(&h);
}
__device__ inline float bf2f(ushort u) {
  unsigned v = ((unsigned)u) << 16;
  return __uint_as_float(v);
}

// fp32 [R][C] -> bf16 [C][R]
__global__ __launch_bounds__(256) void k_transpose_cast(
    const float* __restrict__ in, ushort* __restrict__ out, int R, int C) {
  __shared__ float tile[32][33];
  int c0 = blockIdx.x * 32, r0 = blockIdx.y * 32;
  int tx = threadIdx.x & 31, ty = threadIdx.x >> 5;  // 32 x 8
  for (int i = ty; i < 32; i += 8) {
    int r = r0 + i, c = c0 + tx;
    tile[i][tx] = (r < R && c < C) ? in[(size_t)r * C + c] : 0.f;
  }
  __syncthreads();
  for (int i = ty; i < 32; i += 8) {
    int c = c0 + i, r = r0 + tx;
    if (c < C && r < R) out[(size_t)c * R + r] = f2bf(tile[tx][i]);
  }
}

// Ae[row = t*64+b][k] = embed_tok[x[b][t]][k] + embed_pos[t][k], bf16
__global__ __launch_bounds__(256) void k_embed(
    const int* __restrict__ x, const float* __restrict__ etok,
    const float* __restrict__ epos, ushort* __restrict__ Ae) {
  int row = blockIdx.x;
  int t = row >> 6, b = row & 63;
  int tok = x[b * SS + t];
  const float4* tp = (const float4*)(etok + (size_t)tok * HH);
  const float4* pp = (const float4*)(epos + (size_t)t * HH);
  int i = threadIdx.x;  // 256 threads * float4 = 1024
  float4 a = tp[i], p = pp[i];
  ushort4 r = make_ushort4(f2bf(a.x + p.x), f2bf(a.y + p.y),
                           f2bf(a.z + p.z), f2bf(a.w + p.w));
  ((ushort4*)(Ae + (size_t)row * HH))[i] = r;
}

// C[m][n] (bf16) = A[m][k] @ Bt[n][k]^T + bias[n].  M,N mult of 128, K=1024.
// m97-structure + XCD-chunked block swizzle (nwg % 8 == 0 -> bijective):
// 1024 consecutive linear blocks pin to one XCD -> each A-panel is fetched
// into exactly one XCD L2 (A HBM traffic 8x lower).
__global__ __launch_bounds__(256) void k_gemm_xi(
    const ushort* __restrict__ Ag, const ushort* __restrict__ Bt,
    const float* __restrict__ bias, ushort* __restrict__ Cout, int N) {
  __shared__ alignas(16) ushort As[128 * 32];   // linear (gload_lds needs it)
  __shared__ alignas(16) ushort Bs[128 * 32];
  const int nwg = gridDim.x * gridDim.y;
  const int orig = blockIdx.y * gridDim.x + blockIdx.x;
  const int swz = (orig & 7) * (nwg >> 3) + (orig >> 3);
  const int m0 = (swz / gridDim.x) * 128, n0 = (swz % gridDim.x) * 128;
  const int tid = threadIdx.x;
  const int w = tid >> 6, lane = tid & 63;
  const int wm = w >> 1, wn = w & 1;            // 2x2 waves, 64x64 each
  const int lr = lane & 15, kq = lane >> 4;
  const int srow = w * 32 + (lane >> 2);
  const int skq8 = (lane & 3) * 8;              // shorts offset within row
  f32x4 acc[4][4] = {};
  for (int k0 = 0; k0 < HH; k0 += 32) {
    __syncthreads();    // previous iter's ds_reads done before overwrite
    const ushort* ga0 = Ag + (size_t)(m0 + srow) * HH + k0 + skq8;
    const ushort* gb0 = Bt + (size_t)(n0 + srow) * HH + k0 + skq8;
    __builtin_amdgcn_global_load_lds(
        (const __attribute__((address_space(1))) unsigned*)ga0,
        (__attribute__((address_space(3))) unsigned*)&As[(w * 32) * 32], 16, 0, 0);
    __builtin_amdgcn_global_load_lds(
        (const __attribute__((address_space(1))) unsigned*)(ga0 + 16 * HH),
        (__attribute__((address_space(3))) unsigned*)&As[(w * 32 + 16) * 32], 16, 0, 0);
    __builtin_amdgcn_global_load_lds(
        (const __attribute__((address_space(1))) unsigned*)gb0,
        (__attribute__((address_space(3))) unsigned*)&Bs[(w * 32) * 32], 16, 0, 0);
    __builtin_amdgcn_global_load_lds(
        (const __attribute__((address_space(1))) unsigned*)(gb0 + 16 * HH),
        (__attribute__((address_space(3))) unsigned*)&Bs[(w * 32 + 16) * 32], 16, 0, 0);
    __syncthreads();    // drains vmcnt (gload_lds) per syncthreads semantics
    bf8_t fa[4], fb[4];
#pragma unroll
    for (int i = 0; i < 4; ++i) {
      fa[i] = *(const bf8_t*)&As[(wm * 64 + i * 16 + lr) * 32 + kq * 8];
      fb[i] = *(const bf8_t*)&Bs[(wn * 64 + i * 16 + lr) * 32 + kq * 8];
    }
#pragma unroll
    for (int mi = 0; mi < 4; ++mi)
#pragma unroll
      for (int ni = 0; ni < 4; ++ni)
        acc[mi][ni] = __builtin_amdgcn_mfma_f32_16x16x32_bf16(fa[mi], fb[ni], acc[mi][ni], 0, 0, 0);
  }
#pragma unroll
  for (int mi = 0; mi < 4; ++mi) {
    int grow = m0 + wm * 64 + mi * 16 + kq * 4;
#pragma unroll
    for (int ni = 0; ni < 4; ++ni) {
      int gcol = n0 + wn * 64 + ni * 16 + lr;
      float bv = bias[gcol];
#pragma unroll
      for (int r = 0; r < 4; ++r)
        Cout[(size_t)(grow + r) * N + gcol] = f2bf(acc[mi][ni][r] + bv);
    }
  }
}

// Persistent recurrence — r10 transport verbatim (empirically optimal across
// r8-r16: flag/token/canary/batch-skip/plain-load all equal or worse, and
// plain fragA loads are L2-stale-unsound). Double-buffered htile removes the
// pre-stage barrier: a wave can only re-touch buf[t&1] at step t+2 after its
// poll of h(t+2) succeeded, which requires every wave of its own WG to have
// finished step t+1 entirely -> step t's reads long done. 1 barrier/step.
__global__ __launch_bounds__(256, 1) void k_recur(
    const ushort* __restrict__ Wh_t,   // [4096][1024] bf16
    const ushort* __restrict__ xi,     // [S*64][4096] bf16 (bh folded in)
    ushort* __restrict__ hs,           // [(S+1)*64][1024] bf16 row layout
    uint4* __restrict__ fragA) {       // [512][4][2048] 16B units; sentinel-filled
  __shared__ alignas(16) ushort htile[2][2048 * 8];  // 2 x 32 KiB
  __shared__ ushort hxch[4][16][4];                  // 512 B wave-local
  const ull SENT = 0x7F7F7F7F7F7F7F7FULL;
  const int grp = blockIdx.x >> 6;      // batch group 0..3
  const int mem = blockIdx.x & 63;      // member (column owner)
  const int n0 = mem * 16;
  const int brow0 = grp * 16;
  const int tid = threadIdx.x;
  const int w = tid >> 6, lane = tid & 63;
  const int lr = lane & 15, kq = lane >> 4;
  const int gate = lr >> 2;
  const int c0 = n0 + 4 * w;            // wave's 4-col base
  const int gc = gate * 1024 + c0 + (lr & 3);

  // fb fragments via inline-asm loads (32-batch proven safe)
  bf8_t fbr[32];
  {
    const ushort* wrow = Wh_t + (size_t)gc * HH + kq * 8;
#pragma unroll
    for (int k = 0; k < 32; ++k)
      asm volatile("global_load_dwordx4 %0, %1, off offset:%c2"
                   : "=v"(fbr[k]) : "v"(wrow), "i"(k * 64));
    asm volatile("s_waitcnt vmcnt(0)" ::: "memory");
  }

  // publish precompute (lanes 0..15): unit u = pk0*64+pq*16+row, byte pboff
  const int pk0 = c0 >> 5, pq = (c0 >> 3) & 3;
  const int pboff = (c0 & 7) * 2;       // 0 or 8

  float cr[4] = {0.f, 0.f, 0.f, 0.f};   // c-state

  // xi(0) preload: xi[row=brow0+kq*4+r][gc]
  ushort xv[4];
  {
    const ushort* xr = xi + ((size_t)brow0 + kq * 4) * G4 + gc;
#pragma unroll
    for (int r = 0; r < 4; ++r) xv[r] = xr[(size_t)r * G4];
  }

  for (int t = 0; t < SS; ++t) {
    // ---- obtain h(t): batched sentinel poll (r10 verbatim) ----
    ull uvv[16];
    if (t == 0) {
#pragma unroll
      for (int j = 0; j < 16; ++j) uvv[j] = 0;
    } else {
      const ull* q = (const ull*)(fragA + ((size_t)(t - 1) * 4 + grp) * 2048);
      bool again;
      do {
#pragma unroll
        for (int i = 0; i < 8; ++i) {   // unconditional: all 16 in flight
          uvv[2 * i]     = __hip_atomic_load(q + 2 * tid + 512 * i,
                              __ATOMIC_RELAXED, __HIP_MEMORY_SCOPE_AGENT);
          uvv[2 * i + 1] = __hip_atomic_load(q + 2 * tid + 512 * i + 1,
                              __ATOMIC_RELAXED, __HIP_MEMORY_SCOPE_AGENT);
        }
        again = false;
#pragma unroll
        for (int j = 0; j < 16; ++j) again |= (uvv[j] == SENT);
      } while (again);
    }

    // ---- stage into buf[t&1] (no pre-barrier needed: see header note) ----
    ushort* hb = htile[t & 1];
#pragma unroll
    for (int i = 0; i < 8; ++i) {
      uint4 sw;
      sw.x = (unsigned)uvv[2 * i];     sw.y = (unsigned)(uvv[2 * i] >> 32);
      sw.z = (unsigned)uvv[2 * i + 1]; sw.w = (unsigned)(uvv[2 * i + 1] >> 32);
      *(uint4*)&hb[(size_t)(tid + 256 * i) * 8] = sw;
    }
    __syncthreads();                    // stage complete

    // xi(t+1) prefetch — consumed next step, hidden under MFMA
    ushort xn[4];
    {
      int tn = (t + 1 < SS) ? t + 1 : t;
      const ushort* xr = xi + ((size_t)tn * 64 + brow0 + kq * 4) * G4 + gc;
#pragma unroll
      for (int r = 0; r < 4; ++r) xn[r] = xr[(size_t)r * G4];
    }

    // ---- MFMA: 32 k-chunks, fa LDS conflict-free, fb regs ----
    f32x4 acc0 = {}, acc1 = {};
#pragma unroll
    for (int k = 0; k < 32; k += 2) {
      bf8_t fa0 = *(const bf8_t*)&hb[(k * 64 + lane) * 8];
      bf8_t fa1 = *(const bf8_t*)&hb[((k + 1) * 64 + lane) * 8];
      acc0 = __builtin_amdgcn_mfma_f32_16x16x32_bf16(fa0, fbr[k], acc0, 0, 0, 0);
      acc1 = __builtin_amdgcn_mfma_f32_16x16x32_bf16(fa1, fbr[k + 1], acc1, 0, 0, 0);
    }

    // ---- parallel epilogue (all lanes) ----
    float z[4], zb[4], zc[4], zd[4];
#pragma unroll
    for (int r = 0; r < 4; ++r) z[r] = acc0[r] + acc1[r] + bf2f(xv[r]);
#pragma unroll
    for (int r = 0; r < 4; ++r) {
      zb[r] = __shfl_xor(z[r], 4);
      zc[r] = __shfl_xor(z[r], 8);
      zd[r] = __shfl_xor(zb[r], 8);
    }
    ushort hvals[4];
#pragma unroll
    for (int r = 0; r < 4; ++r) {
      float zi = gate == 0 ? z[r] : gate == 1 ? zb[r] : gate == 2 ? zc[r] : zd[r];
      float zf = gate == 0 ? zb[r] : gate == 1 ? z[r] : gate == 2 ? zd[r] : zc[r];
      float zg = gate == 0 ? zc[r] : gate == 1 ? zd[r] : gate == 2 ? z[r] : zb[r];
      float zo = gate == 0 ? zd[r] : gate == 1 ? zc[r] : gate == 2 ? zb[r] : z[r];
      float si = 1.f / (1.f + __expf(-zi));
      float sf = 1.f / (1.f + __expf(-zf));
      float so = 1.f / (1.f + __expf(-zo));
      float tg = 1.f - 2.f / (1.f + __expf(2.f * zg));   // tanh
      float c  = sf * cr[r] + si * tg;
      cr[r] = c;
      float tc = 1.f - 2.f / (1.f + __expf(2.f * c));    // tanh
      hvals[r] = f2bf(so * tc);
    }
    // wave-local transpose: gate-0 lanes write (4 rows x 1 col each)
    if (lr < 4) {
#pragma unroll
      for (int r = 0; r < 4; ++r) hxch[w][kq * 4 + r][lr] = hvals[r];
    }
    // lanes 0..15: read (row=lane, 4 cols) and publish (same wave -> lgkmcnt)
    if (lane < 16) {
      uint2 ho8 = *(const uint2*)&hxch[w][lane][0];
      ull val = ((ull)ho8.y << 32) | ho8.x;
      char* fbase = (char*)(fragA + ((size_t)t * 4 + grp) * 2048);
      ull* fdst = (ull*)(fbase + (size_t)(pk0 * 64 + pq * 16 + lane) * 16 + pboff);
      __hip_atomic_exchange(fdst, val, __ATOMIC_RELAXED,
                            __HIP_MEMORY_SCOPE_AGENT);   // fire-and-forget
      // row-layout copy for k_logits (read only after kernel end)
      *(uint2*)(hs + ((size_t)(t + 1) * 64 + brow0 + lane) * HH + c0) = ho8;
    }
    xv[0] = xn[0]; xv[1] = xn[1]; xv[2] = xn[2]; xv[3] = xn[3];
  }
}

// logits[b][t][a] = hs[t+1][b][:] . Wd_t[a][:] + bd[a]
__global__ __launch_bounds__(256) void k_logits(
    const ushort* __restrict__ hs1, const ushort* __restrict__ Wdt,
    const float* __restrict__ bd, float* __restrict__ out) {
  int gid = blockIdx.x * 256 + threadIdx.x;
  int a = gid & 15, row = gid >> 4;   // row = t*64+b
  int t = row >> 6, b = row & 63;
  const uint4* hp = (const uint4*)(hs1 + (size_t)row * HH);
  const uint4* wp = (const uint4*)(Wdt + (size_t)a * HH);
  float sum = 0.f;
#pragma unroll 4
  for (int i = 0; i < HH / 8; ++i) {
    uint4 hv = hp[i], wv = wp[i];
    const uint* hu = (const uint*)&hv;
    const uint* wu = (const uint*)&wv;
#pragma unroll
    for (int j = 0; j < 4; ++j) {
      sum += bf2f((ushort)(hu[j] & 0xffff)) * bf2f((ushort)(wu[j] & 0xffff));
      sum += bf2f((ushort)(hu[j] >> 16)) * bf2f((ushort)(wu[j] >> 16));
    }
  }
  out[32768 + ((size_t)b * SS + t) * 16 + a] = sum + bd[a];
}

extern "C" void kernel_launch(void* const* d_in, const int* in_sizes, int n_in,
                              void* d_out, int out_size, void* d_ws, size_t ws_size,
                              hipStream_t stream) {
  const int*   x    = (const int*)d_in[0];
  const float* etok = (const float*)d_in[4];
  const float* epos = (const float*)d_in[5];
  const float* Wi   = (const float*)d_in[6];
  const float* Wh   = (const float*)d_in[7];
  const float* bh   = (const float*)d_in[8];
  const float* Wd   = (const float*)d_in[9];
  const float* bd   = (const float*)d_in[10];

  char* ws = (char*)d_ws;
  size_t off = 0;
  ushort* Wi_t = (ushort*)(ws + off); off += (size_t)G4 * HH * 2;            // 8 MB
  ushort* Wh_t = (ushort*)(ws + off); off += (size_t)G4 * HH * 2;            // 8 MB
  ushort* Wd_t = (ushort*)(ws + off); off += 65536;                          // 64 KB
  // Ae (64 MB, dead after k_gemm_xi) aliases fragA (64 MB). Sentinel memset
  // sits between them in stream order; all k_recur consumes are atomic
  // (L2-bypass) so stale clean lines are unreachable.
  char* AeFrag = ws + off;            off += (size_t)512 * 4 * 2048 * 16;    // 64 MB
  ushort* Ae   = (ushort*)AeFrag;
  uint4*  fragA = (uint4*)AeFrag;
  ushort* xi   = (ushort*)(ws + off); off += (size_t)BB * SS * G4 * 2;       // 256 MB
  ushort* hs   = (ushort*)(ws + off); off += (size_t)(SS + 1) * BB * HH * 2; // 64.1 MB

  hipMemsetAsync(d_out, 0, (size_t)out_size * 4, stream);          // dummies = 0

  dim3 b256(256);
  k_transpose_cast<<<dim3(G4 / 32, HH / 32), b256, 0, stream>>>(Wi, Wi_t, HH, G4);
  k_transpose_cast<<<dim3(G4 / 32, HH / 32), b256, 0, stream>>>(Wh, Wh_t, HH, G4);
  k_transpose_cast<<<dim3(1, HH / 32), b256, 0, stream>>>(Wd, Wd_t, HH, 16);
  k_embed<<<BB * SS, b256, 0, stream>>>(x, etok, epos, Ae);
  k_gemm_xi<<<dim3(G4 / 128, BB * SS / 128), b256, 0, stream>>>(Ae, Wi_t, bh, xi, G4);
  // re-sentinel fragA EVERY call (harness replays without re-poisoning)
  hipMemsetAsync(fragA, 0x7F, (size_t)512 * 4 * 2048 * 16, stream);
  k_recur<<<256, b256, 0, stream>>>(Wh_t, xi, hs, fragA);
  k_logits<<<BB * SS * 16 / 256, b256, 0, stream>>>(hs + (size_t)BB * HH, Wd_t, bd,
                                                    (float*)d_out);
}

// Round 18
// 2642.781 us; speedup vs baseline: 1.1359x; 1.0472x over previous
//
#include <hip/hip_runtime.h>
#include <hip/hip_bf16.h>

#define BB 64
#define SS 512
#define HH 1024
#define G4 4096

using bf8_t = __attribute__((ext_vector_type(8))) short;   // 8 bf16 (4 VGPRs)
using f32x4 = __attribute__((ext_vector_type(4))) float;   // 4 fp32 acc
typedef unsigned long long ull;

__device__ inline ushort f2bf(float f) {
  __hip_bfloat16 h = __float2bfloat16(f);
  return *reinterpret_cast<ushort*>(&h);
}
__device__ inline float bf2f(ushort u) {
  unsigned v = ((unsigned)u) << 16;
  return __uint_as_float(v);
}

// fp32 [R][C] -> bf16 [C][R]
__global__ __launch_bounds__(256) void k_transpose_cast(
    const float* __restrict__ in, ushort* __restrict__ out, int R, int C) {
  __shared__ float tile[32][33];
  int c0 = blockIdx.x * 32, r0 = blockIdx.y * 32;
  int tx = threadIdx.x & 31, ty = threadIdx.x >> 5;  // 32 x 8
  for (int i = ty; i < 32; i += 8) {
    int r = r0 + i, c = c0 + tx;
    tile[i][tx] = (r < R && c < C) ? in[(size_t)r * C + c] : 0.f;
  }
  __syncthreads();
  for (int i = ty; i < 32; i += 8) {
    int c = c0 + i, r = r0 + tx;
    if (c < C && r < R) out[(size_t)c * R + r] = f2bf(tile[tx][i]);
  }
}

// Ae[row = t*64+b][k] = embed_tok[x[b][t]][k] + embed_pos[t][k], bf16
__global__ __launch_bounds__(256) void k_embed(
    const int* __restrict__ x, const float* __restrict__ etok,
    const float* __restrict__ epos, ushort* __restrict__ Ae) {
  int row = blockIdx.x;
  int t = row >> 6, b = row & 63;
  int tok = x[b * SS + t];
  const float4* tp = (const float4*)(etok + (size_t)tok * HH);
  const float4* pp = (const float4*)(epos + (size_t)t * HH);
  int i = threadIdx.x;  // 256 threads * float4 = 1024
  float4 a = tp[i], p = pp[i];
  ushort4 r = make_ushort4(f2bf(a.x + p.x), f2bf(a.y + p.y),
                           f2bf(a.z + p.z), f2bf(a.w + p.w));
  ((ushort4*)(Ae + (size_t)row * HH))[i] = r;
}

// C[m][n] (bf16) = A[m][k] @ Bt[n][k]^T + bias[n].  M,N mult of 128, K=1024.
// m97-structure + XCD-chunked block swizzle (nwg % 8 == 0 -> bijective).
__global__ __launch_bounds__(256) void k_gemm_xi(
    const ushort* __restrict__ Ag, const ushort* __restrict__ Bt,
    const float* __restrict__ bias, ushort* __restrict__ Cout, int N) {
  __shared__ alignas(16) ushort As[128 * 32];   // linear (gload_lds needs it)
  __shared__ alignas(16) ushort Bs[128 * 32];
  const int nwg = gridDim.x * gridDim.y;
  const int orig = blockIdx.y * gridDim.x + blockIdx.x;
  const int swz = (orig & 7) * (nwg >> 3) + (orig >> 3);
  const int m0 = (swz / gridDim.x) * 128, n0 = (swz % gridDim.x) * 128;
  const int tid = threadIdx.x;
  const int w = tid >> 6, lane = tid & 63;
  const int wm = w >> 1, wn = w & 1;            // 2x2 waves, 64x64 each
  const int lr = lane & 15, kq = lane >> 4;
  const int srow = w * 32 + (lane >> 2);
  const int skq8 = (lane & 3) * 8;              // shorts offset within row
  f32x4 acc[4][4] = {};
  for (int k0 = 0; k0 < HH; k0 += 32) {
    __syncthreads();    // previous iter's ds_reads done before overwrite
    const ushort* ga0 = Ag + (size_t)(m0 + srow) * HH + k0 + skq8;
    const ushort* gb0 = Bt + (size_t)(n0 + srow) * HH + k0 + skq8;
    __builtin_amdgcn_global_load_lds(
        (const __attribute__((address_space(1))) unsigned*)ga0,
        (__attribute__((address_space(3))) unsigned*)&As[(w * 32) * 32], 16, 0, 0);
    __builtin_amdgcn_global_load_lds(
        (const __attribute__((address_space(1))) unsigned*)(ga0 + 16 * HH),
        (__attribute__((address_space(3))) unsigned*)&As[(w * 32 + 16) * 32], 16, 0, 0);
    __builtin_amdgcn_global_load_lds(
        (const __attribute__((address_space(1))) unsigned*)gb0,
        (__attribute__((address_space(3))) unsigned*)&Bs[(w * 32) * 32], 16, 0, 0);
    __builtin_amdgcn_global_load_lds(
        (const __attribute__((address_space(1))) unsigned*)(gb0 + 16 * HH),
        (__attribute__((address_space(3))) unsigned*)&Bs[(w * 32 + 16) * 32], 16, 0, 0);
    __syncthreads();    // drains vmcnt (gload_lds) per syncthreads semantics
    bf8_t fa[4], fb[4];
#pragma unroll
    for (int i = 0; i < 4; ++i) {
      fa[i] = *(const bf8_t*)&As[(wm * 64 + i * 16 + lr) * 32 + kq * 8];
      fb[i] = *(const bf8_t*)&Bs[(wn * 64 + i * 16 + lr) * 32 + kq * 8];
    }
#pragma unroll
    for (int mi = 0; mi < 4; ++mi)
#pragma unroll
      for (int ni = 0; ni < 4; ++ni)
        acc[mi][ni] = __builtin_amdgcn_mfma_f32_16x16x32_bf16(fa[mi], fb[ni], acc[mi][ni], 0, 0, 0);
  }
#pragma unroll
  for (int mi = 0; mi < 4; ++mi) {
    int grow = m0 + wm * 64 + mi * 16 + kq * 4;
#pragma unroll
    for (int ni = 0; ni < 4; ++ni) {
      int gcol = n0 + wn * 64 + ni * 16 + lr;
      float bv = bias[gcol];
#pragma unroll
      for (int r = 0; r < 4; ++r)
        Cout[(size_t)(grow + r) * N + gcol] = f2bf(acc[mi][ni][r] + bv);
    }
  }
}

// Persistent recurrence — r17 verbatim (best-known: r10 transport + dbuf
// htile, 1 barrier/step). All fragA consumes are agent-scope atomics
// (L2-bypass; plain loads unsound per r15).
__global__ __launch_bounds__(256, 1) void k_recur(
    const ushort* __restrict__ Wh_t,   // [4096][1024] bf16
    const ushort* __restrict__ xi,     // [S*64][4096] bf16 (bh folded in)
    ushort* __restrict__ hs,           // [(S+1)*64][1024] bf16 row layout
    uint4* __restrict__ fragA) {       // [512][4][2048] 16B units; sentinel-filled
  __shared__ alignas(16) ushort htile[2][2048 * 8];  // 2 x 32 KiB
  __shared__ ushort hxch[4][16][4];                  // 512 B wave-local
  const ull SENT = 0x7F7F7F7F7F7F7F7FULL;
  const int grp = blockIdx.x >> 6;      // batch group 0..3
  const int mem = blockIdx.x & 63;      // member (column owner)
  const int n0 = mem * 16;
  const int brow0 = grp * 16;
  const int tid = threadIdx.x;
  const int w = tid >> 6, lane = tid & 63;
  const int lr = lane & 15, kq = lane >> 4;
  const int gate = lr >> 2;
  const int c0 = n0 + 4 * w;            // wave's 4-col base
  const int gc = gate * 1024 + c0 + (lr & 3);

  // fb fragments via inline-asm loads (32-batch proven safe)
  bf8_t fbr[32];
  {
    const ushort* wrow = Wh_t + (size_t)gc * HH + kq * 8;
#pragma unroll
    for (int k = 0; k < 32; ++k)
      asm volatile("global_load_dwordx4 %0, %1, off offset:%c2"
                   : "=v"(fbr[k]) : "v"(wrow), "i"(k * 64));
    asm volatile("s_waitcnt vmcnt(0)" ::: "memory");
  }

  // publish precompute (lanes 0..15): unit u = pk0*64+pq*16+row, byte pboff
  const int pk0 = c0 >> 5, pq = (c0 >> 3) & 3;
  const int pboff = (c0 & 7) * 2;       // 0 or 8

  float cr[4] = {0.f, 0.f, 0.f, 0.f};   // c-state

  // xi(0) preload: xi[row=brow0+kq*4+r][gc]
  ushort xv[4];
  {
    const ushort* xr = xi + ((size_t)brow0 + kq * 4) * G4 + gc;
#pragma unroll
    for (int r = 0; r < 4; ++r) xv[r] = xr[(size_t)r * G4];
  }

  for (int t = 0; t < SS; ++t) {
    // ---- obtain h(t): batched sentinel poll (r10 verbatim) ----
    ull uvv[16];
    if (t == 0) {
#pragma unroll
      for (int j = 0; j < 16; ++j) uvv[j] = 0;
    } else {
      const ull* q = (const ull*)(fragA + ((size_t)(t - 1) * 4 + grp) * 2048);
      bool again;
      do {
#pragma unroll
        for (int i = 0; i < 8; ++i) {   // unconditional: all 16 in flight
          uvv[2 * i]     = __hip_atomic_load(q + 2 * tid + 512 * i,
                              __ATOMIC_RELAXED, __HIP_MEMORY_SCOPE_AGENT);
          uvv[2 * i + 1] = __hip_atomic_load(q + 2 * tid + 512 * i + 1,
                              __ATOMIC_RELAXED, __HIP_MEMORY_SCOPE_AGENT);
        }
        again = false;
#pragma unroll
        for (int j = 0; j < 16; ++j) again |= (uvv[j] == SENT);
      } while (again);
    }

    // ---- stage into buf[t&1] (dbuf: no pre-stage barrier needed) ----
    ushort* hb = htile[t & 1];
#pragma unroll
    for (int i = 0; i < 8; ++i) {
      uint4 sw;
      sw.x = (unsigned)uvv[2 * i];     sw.y = (unsigned)(uvv[2 * i] >> 32);
      sw.z = (unsigned)uvv[2 * i + 1]; sw.w = (unsigned)(uvv[2 * i + 1] >> 32);
      *(uint4*)&hb[(size_t)(tid + 256 * i) * 8] = sw;
    }
    __syncthreads();                    // stage complete

    // xi(t+1) prefetch — consumed next step, hidden under MFMA
    ushort xn[4];
    {
      int tn = (t + 1 < SS) ? t + 1 : t;
      const ushort* xr = xi + ((size_t)tn * 64 + brow0 + kq * 4) * G4 + gc;
#pragma unroll
      for (int r = 0; r < 4; ++r) xn[r] = xr[(size_t)r * G4];
    }

    // ---- MFMA: 32 k-chunks, fa LDS conflict-free, fb regs ----
    f32x4 acc0 = {}, acc1 = {};
#pragma unroll
    for (int k = 0; k < 32; k += 2) {
      bf8_t fa0 = *(const bf8_t*)&hb[(k * 64 + lane) * 8];
      bf8_t fa1 = *(const bf8_t*)&hb[((k + 1) * 64 + lane) * 8];
      acc0 = __builtin_amdgcn_mfma_f32_16x16x32_bf16(fa0, fbr[k], acc0, 0, 0, 0);
      acc1 = __builtin_amdgcn_mfma_f32_16x16x32_bf16(fa1, fbr[k + 1], acc1, 0, 0, 0);
    }

    // ---- parallel epilogue (all lanes) ----
    float z[4], zb[4], zc[4], zd[4];
#pragma unroll
    for (int r = 0; r < 4; ++r) z[r] = acc0[r] + acc1[r] + bf2f(xv[r]);
#pragma unroll
    for (int r = 0; r < 4; ++r) {
      zb[r] = __shfl_xor(z[r], 4);
      zc[r] = __shfl_xor(z[r], 8);
      zd[r] = __shfl_xor(zb[r], 8);
    }
    ushort hvals[4];
#pragma unroll
    for (int r = 0; r < 4; ++r) {
      float zi = gate == 0 ? z[r] : gate == 1 ? zb[r] : gate == 2 ? zc[r] : zd[r];
      float zf = gate == 0 ? zb[r] : gate == 1 ? z[r] : gate == 2 ? zd[r] : zc[r];
      float zg = gate == 0 ? zc[r] : gate == 1 ? zd[r] : gate == 2 ? z[r] : zb[r];
      float zo = gate == 0 ? zd[r] : gate == 1 ? zc[r] : gate == 2 ? zb[r] : z[r];
      float si = 1.f / (1.f + __expf(-zi));
      float sf = 1.f / (1.f + __expf(-zf));
      float so = 1.f / (1.f + __expf(-zo));
      float tg = 1.f - 2.f / (1.f + __expf(2.f * zg));   // tanh
      float c  = sf * cr[r] + si * tg;
      cr[r] = c;
      float tc = 1.f - 2.f / (1.f + __expf(2.f * c));    // tanh
      hvals[r] = f2bf(so * tc);
    }
    // wave-local transpose: gate-0 lanes write (4 rows x 1 col each)
    if (lr < 4) {
#pragma unroll
      for (int r = 0; r < 4; ++r) hxch[w][kq * 4 + r][lr] = hvals[r];
    }
    // lanes 0..15: read (row=lane, 4 cols) and publish (same wave -> lgkmcnt)
    if (lane < 16) {
      uint2 ho8 = *(const uint2*)&hxch[w][lane][0];
      ull val = ((ull)ho8.y << 32) | ho8.x;
      char* fbase = (char*)(fragA + ((size_t)t * 4 + grp) * 2048);
      ull* fdst = (ull*)(fbase + (size_t)(pk0 * 64 + pq * 16 + lane) * 16 + pboff);
      __hip_atomic_exchange(fdst, val, __ATOMIC_RELAXED,
                            __HIP_MEMORY_SCOPE_AGENT);   // fire-and-forget
      // row-layout copy for k_logits (read only after kernel end)
      *(uint2*)(hs + ((size_t)(t + 1) * 64 + brow0 + lane) * HH + c0) = ho8;
    }
    xv[0] = xn[0]; xv[1] = xn[1]; xv[2] = xn[2]; xv[3] = xn[3];
  }
}

// logits via MFMA: one wave = 16 rows x 16 actions, K=1024 in 32 MFMA.
// A-frags straight from hs1 (16B/lane); B (Wd_t, 32KB) is L1/L2-broadcast.
// Reads each h byte exactly once (vs 4B-granule shared-row reads before).
__global__ __launch_bounds__(256) void k_logits(
    const ushort* __restrict__ hs1, const ushort* __restrict__ Wdt,
    const float* __restrict__ bd, float* __restrict__ out) {
  const int w = threadIdx.x >> 6, lane = threadIdx.x & 63;
  const int lr = lane & 15, kq = lane >> 4;
  const int r0 = blockIdx.x * 64 + w * 16;       // 512 blocks x 4 waves
  const ushort* arow = hs1 + (size_t)(r0 + lr) * HH + kq * 8;
  const ushort* brow = Wdt + (size_t)lr * HH + kq * 8;
  f32x4 acc = {};
#pragma unroll
  for (int k = 0; k < 32; ++k) {
    bf8_t fa = *(const bf8_t*)(arow + k * 32);
    bf8_t fb = *(const bf8_t*)(brow + k * 32);
    acc = __builtin_amdgcn_mfma_f32_16x16x32_bf16(fa, fb, acc, 0, 0, 0);
  }
  // C layout: col(lane&15) = action a, row = kq*4 + r
  float bv = bd[lr];
#pragma unroll
  for (int r = 0; r < 4; ++r) {
    int rg = r0 + kq * 4 + r;          // = t*64 + b
    int t = rg >> 6, b = rg & 63;
    out[32768 + ((size_t)b * SS + t) * 16 + lr] = acc[r] + bv;
  }
}

extern "C" void kernel_launch(void* const* d_in, const int* in_sizes, int n_in,
                              void* d_out, int out_size, void* d_ws, size_t ws_size,
                              hipStream_t stream) {
  const int*   x    = (const int*)d_in[0];
  const float* etok = (const float*)d_in[4];
  const float* epos = (const float*)d_in[5];
  const float* Wi   = (const float*)d_in[6];
  const float* Wh   = (const float*)d_in[7];
  const float* bh   = (const float*)d_in[8];
  const float* Wd   = (const float*)d_in[9];
  const float* bd   = (const float*)d_in[10];

  char* ws = (char*)d_ws;
  size_t off = 0;
  ushort* Wi_t = (ushort*)(ws + off); off += (size_t)G4 * HH * 2;            // 8 MB
  ushort* Wh_t = (ushort*)(ws + off); off += (size_t)G4 * HH * 2;            // 8 MB
  ushort* Wd_t = (ushort*)(ws + off); off += 65536;                          // 64 KB
  // Ae (64 MB, dead after k_gemm_xi) aliases fragA (64 MB). Sentinel memset
  // sits between them in stream order; all k_recur consumes are atomic
  // (L2-bypass) so stale clean lines are unreachable.
  char* AeFrag = ws + off;            off += (size_t)512 * 4 * 2048 * 16;    // 64 MB
  ushort* Ae   = (ushort*)AeFrag;
  uint4*  fragA = (uint4*)AeFrag;
  ushort* xi   = (ushort*)(ws + off); off += (size_t)BB * SS * G4 * 2;       // 256 MB
  ushort* hs   = (ushort*)(ws + off); off += (size_t)(SS + 1) * BB * HH * 2; // 64.1 MB

  hipMemsetAsync(d_out, 0, (size_t)out_size * 4, stream);          // dummies = 0

  dim3 b256(256);
  k_transpose_cast<<<dim3(G4 / 32, HH / 32), b256, 0, stream>>>(Wi, Wi_t, HH, G4);
  k_transpose_cast<<<dim3(G4 / 32, HH / 32), b256, 0, stream>>>(Wh, Wh_t, HH, G4);
  k_transpose_cast<<<dim3(1, HH / 32), b256, 0, stream>>>(Wd, Wd_t, HH, 16);
  k_embed<<<BB * SS, b256, 0, stream>>>(x, etok, epos, Ae);
  k_gemm_xi<<<dim3(G4 / 128, BB * SS / 128), b256, 0, stream>>>(Ae, Wi_t, bh, xi, G4);
  // re-sentinel fragA EVERY call (harness replays without re-poisoning)
  hipMemsetAsync(fragA, 0x7F, (size_t)512 * 4 * 2048 * 16, stream);
  k_recur<<<256, b256, 0, stream>>>(Wh_t, xi, hs, fragA);
  k_logits<<<BB * SS / 64, b256, 0, stream>>>(hs + (size_t)BB * HH, Wd_t, bd,
                                              (float*)d_out);
}